// Round 5
// baseline (431.079 us; speedup 1.0000x reference)
//
#include <hip/hip_runtime.h>
#include <stdint.h>

#define N 8192
#define FD 64
#define NC 10
#define SK 8
#define BM 128
#define BK 128

typedef __attribute__((ext_vector_type(8))) __bf16 bf16x8;
typedef __attribute__((ext_vector_type(4))) float f32x4;
typedef __attribute__((ext_vector_type(4))) float vf4;   // native vector for nontemporal builtins

__device__ __forceinline__ unsigned short f2bf(float f) {
    unsigned u = __builtin_bit_cast(unsigned, f);
    u += 0x7fffu + ((u >> 16) & 1u);   // round-to-nearest-even
    return (unsigned short)(u >> 16);
}

// async global->LDS, 16B per lane. LDS dest must be wave-uniform base + lane*16.
__device__ __forceinline__ void g2l16(const void* g, void* l) {
    __builtin_amdgcn_global_load_lds(
        (const __attribute__((address_space(1))) unsigned int*)g,
        (__attribute__((address_space(3))) unsigned int*)l, 16, 0, 0);
}

// ---------------------------------------------------------------------------
// Kernel 1: fused row-sum of fp32 A + cast A -> bf16 (RNE). One block per row.
// Nontemporal loads for A: the fp32 stream (268 MB, dead after this kernel)
// must not evict the freshly written Abf (134 MB) from the 256 MB L3 —
// both spmm passes want to read Abf at L3 bandwidth.
// ---------------------------------------------------------------------------
__global__ __launch_bounds__(256) void rowsum_cast(const float* __restrict__ A,
                                                   unsigned short* __restrict__ Abf,
                                                   float* __restrict__ dvec) {
    const int row = blockIdx.x;
    const int t = threadIdx.x;
    const vf4* Arow = (const vf4*)(A + (size_t)row * N);
    ushort4* Brow = (ushort4*)(Abf + (size_t)row * N);
    float s = 0.f;
#pragma unroll
    for (int i = 0; i < 8; i++) {
        int c4 = t + 256 * i;
        vf4 v = __builtin_nontemporal_load(Arow + c4);
        s += (v.x + v.y) + (v.z + v.w);
        ushort4 o;
        o.x = f2bf(v.x); o.y = f2bf(v.y); o.z = f2bf(v.z); o.w = f2bf(v.w);
        Brow[c4] = o;   // regular store: keep Abf L3-resident
    }
#pragma unroll
    for (int off = 32; off > 0; off >>= 1) s += __shfl_down(s, off, 64);
    __shared__ float red[4];
    if ((t & 63) == 0) red[t >> 6] = s;
    __syncthreads();
    if (t == 0) {
        float tot = (red[0] + red[1]) + (red[2] + red[3]);
        dvec[row] = tot > 0.f ? rsqrtf(tot) : 0.f;
    }
}

// ---------------------------------------------------------------------------
// Shared inner: per-wave, lane l owns row r0+l, wave w owns f in [16w,16w+16).
// Xs stride 69: bank(l*69+j) = (5l+j)%32 -> 2-way across 64 lanes = free.
// Ws reads are wave-uniform broadcast b128.
// ---------------------------------------------------------------------------
__device__ __forceinline__ void xw_inner(const float (*Xs)[69], const float* Ws,
                                         const float* __restrict__ dvec,
                                         unsigned short* __restrict__ yT,
                                         int r0, int t) {
    const int l = t & 63, w = t >> 6;
    float acc[16];
#pragma unroll
    for (int i = 0; i < 16; i++) acc[i] = 0.f;
#pragma unroll 8
    for (int j = 0; j < 64; j++) {
        float xv = Xs[l][j];
        const float4* wr = (const float4*)(Ws + j * 64 + w * 16);
        float4 w0 = wr[0], w1 = wr[1], w2 = wr[2], w3 = wr[3];
        acc[0] += xv * w0.x; acc[1] += xv * w0.y; acc[2] += xv * w0.z; acc[3] += xv * w0.w;
        acc[4] += xv * w1.x; acc[5] += xv * w1.y; acc[6] += xv * w1.z; acc[7] += xv * w1.w;
        acc[8] += xv * w2.x; acc[9] += xv * w2.y; acc[10] += xv * w2.z; acc[11] += xv * w2.w;
        acc[12] += xv * w3.x; acc[13] += xv * w3.y; acc[14] += xv * w3.z; acc[15] += xv * w3.w;
    }
    float dl = dvec[r0 + l];
#pragma unroll
    for (int ff = 0; ff < 16; ff++)
        yT[(size_t)(w * 16 + ff) * N + r0 + l] = f2bf(dl * acc[ff]);
}

// ---------------------------------------------------------------------------
// Kernel 2 (layer 1): yT[f][r] = bf16( d[r] * (x @ W)[r][f] ), x from global.
// ---------------------------------------------------------------------------
__global__ __launch_bounds__(256) void xw_from_global(const float* __restrict__ x,
                                                      const float* __restrict__ W,
                                                      const float* __restrict__ dvec,
                                                      unsigned short* __restrict__ yT) {
    __shared__ float Xs[64][69];
    __shared__ __align__(16) float Ws[64 * 64];
    const int t = threadIdx.x;
    const int r0 = blockIdx.x * 64;
    const float4* x4 = (const float4*)x + (size_t)r0 * 16;
    const float4* W4 = (const float4*)W;
#pragma unroll
    for (int p = 0; p < 4; p++) {
        int idx = p * 256 + t;
        ((float4*)Ws)[idx] = W4[idx];
        float4 v = x4[idx];
        int row = idx >> 4, f4 = (idx & 15) * 4;
        Xs[row][f4] = v.x; Xs[row][f4 + 1] = v.y; Xs[row][f4 + 2] = v.z; Xs[row][f4 + 3] = v.w;
    }
    __syncthreads();
    xw_inner(Xs, Ws, dvec, yT, r0, t);
}

// ---------------------------------------------------------------------------
// Kernel 3: split-K bf16 MFMA GEMM, BM=128, BK=128, SK=8.
// Staging via global_load_lds(16B); XOR swizzle applied on the GLOBAL address
// (LDS dest stays lane-contiguous). LDS chunk (row,cslot) holds global chunk
// (row, cslot ^ (row&15)), so frag reads at chunk (cc ^ lr) are conflict-free.
// partial is written nontemporal: consumed exactly once, don't evict Abf from L3.
// ---------------------------------------------------------------------------
__global__ __launch_bounds__(256) void spmm(const unsigned short* __restrict__ Abf,
                                            const unsigned short* __restrict__ yT,
                                            float* __restrict__ partial) {
    constexpr int KS = N / SK;               // 1024
    __shared__ __align__(16) unsigned short As[BM * BK];   // 32 KB
    __shared__ __align__(16) unsigned short Ys[64 * BK];   // 16 KB
    const int t = threadIdx.x;
    const int m0 = blockIdx.x * BM;
    const int kbase = blockIdx.y * KS;
    const int lane = t & 63, w = t >> 6;
    const int quad = lane >> 4, lr = lane & 15;

    f32x4 acc[2][4];
#pragma unroll
    for (int mt = 0; mt < 2; mt++)
#pragma unroll
        for (int nt = 0; nt < 4; nt++) {
            acc[mt][nt].x = 0.f; acc[mt][nt].y = 0.f; acc[mt][nt].z = 0.f; acc[mt][nt].w = 0.f;
        }

    for (int k0 = kbase; k0 < kbase + KS; k0 += BK) {
#pragma unroll
        for (int p = 0; p < 8; p++) {
            int s = p * 256 + t;
            int row = s >> 4, c = (s & 15) ^ (row & 15);
            g2l16(Abf + (size_t)(m0 + row) * N + k0 + c * 8, As + s * 8);
        }
#pragma unroll
        for (int p = 0; p < 4; p++) {
            int s = p * 256 + t;
            int row = s >> 4, c = (s & 15) ^ (row & 15);
            g2l16(yT + (size_t)row * N + k0 + c * 8, Ys + s * 8);
        }
        __syncthreads();
#pragma unroll
        for (int kk = 0; kk < BK; kk += 32) {
            int cc = (kk >> 3) + quad;
            bf16x8 af0 = *(const bf16x8*)(As + ((w * 32 + lr) * 16 + (cc ^ lr)) * 8);
            bf16x8 af1 = *(const bf16x8*)(As + ((w * 32 + 16 + lr) * 16 + (cc ^ lr)) * 8);
#pragma unroll
            for (int nt = 0; nt < 4; nt++) {
                bf16x8 bv = *(const bf16x8*)(Ys + ((nt * 16 + lr) * 16 + (cc ^ lr)) * 8);
                acc[0][nt] = __builtin_amdgcn_mfma_f32_16x16x32_bf16(af0, bv, acc[0][nt], 0, 0, 0);
                acc[1][nt] = __builtin_amdgcn_mfma_f32_16x16x32_bf16(af1, bv, acc[1][nt], 0, 0, 0);
            }
        }
        __syncthreads();
    }
    // C/D: row = quad*4 + r, col = lr
#pragma unroll
    for (int mt = 0; mt < 2; mt++)
#pragma unroll
        for (int nt = 0; nt < 4; nt++)
#pragma unroll
            for (int r = 0; r < 4; r++) {
                int m = m0 + w * 32 + mt * 16 + quad * 4 + r;
                __builtin_nontemporal_store(
                    acc[mt][nt][r],
                    partial + ((size_t)blockIdx.y * N + m) * FD + nt * 16 + lr);
            }
}

// ---------------------------------------------------------------------------
// combine helper: sum SK partials (nontemporal loads - read exactly once),
// relu + d-scale into Xs.
// ---------------------------------------------------------------------------
__device__ __forceinline__ void combine_to_lds(const vf4* __restrict__ partial4,
                                               const float* __restrict__ dvec,
                                               float (*Xs)[69], int r0, int t) {
#pragma unroll
    for (int p = 0; p < 4; p++) {
        int idx = p * 256 + t;
        int row = idx >> 4, f4c = idx & 15;
        size_t base = (size_t)(r0 + row) * 16 + f4c;
        vf4 s = __builtin_nontemporal_load(partial4 + base);
#pragma unroll
        for (int sk = 1; sk < SK; sk++) {
            vf4 v = __builtin_nontemporal_load(partial4 + (size_t)sk * (N * 16) + base);
            s.x += v.x; s.y += v.y; s.z += v.z; s.w += v.w;
        }
        float dm = dvec[r0 + row];
        int f4 = f4c * 4;
        Xs[row][f4]     = fmaxf(0.f, dm * s.x);
        Xs[row][f4 + 1] = fmaxf(0.f, dm * s.y);
        Xs[row][f4 + 2] = fmaxf(0.f, dm * s.z);
        Xs[row][f4 + 3] = fmaxf(0.f, dm * s.w);
    }
}

// ---------------------------------------------------------------------------
// Kernel 4: fused split-K combine + relu + d-scale + (x @ W2) -> yT (layer 2)
// ---------------------------------------------------------------------------
__global__ __launch_bounds__(256) void combine_xw(const vf4* __restrict__ partial4,
                                                  const float* __restrict__ W,
                                                  const float* __restrict__ dvec,
                                                  unsigned short* __restrict__ yT) {
    __shared__ float Xs[64][69];
    __shared__ __align__(16) float Ws[64 * 64];
    const int t = threadIdx.x;
    const int r0 = blockIdx.x * 64;
    const float4* W4 = (const float4*)W;
#pragma unroll
    for (int p = 0; p < 4; p++) {
        int idx = p * 256 + t;
        ((float4*)Ws)[idx] = W4[idx];
    }
    combine_to_lds(partial4, dvec, Xs, r0, t);
    __syncthreads();
    xw_inner(Xs, Ws, dvec, yT, r0, t);
}

// ---------------------------------------------------------------------------
// Kernel 5: fused split-K combine + relu + d-scale + classifier (x @ Wc + bc)
// ---------------------------------------------------------------------------
__global__ __launch_bounds__(256) void combine_logits(const vf4* __restrict__ partial4,
                                                      const float* __restrict__ dvec,
                                                      const float* __restrict__ Wc,
                                                      const float* __restrict__ bc,
                                                      float* __restrict__ out) {
    __shared__ float Xs[64][69];
    __shared__ float Wcs[64][10];
    __shared__ float bcs[10];
    const int t = threadIdx.x;
    const int r0 = blockIdx.x * 64;
    combine_to_lds(partial4, dvec, Xs, r0, t);
    for (int i = t; i < 640; i += 256) Wcs[i / 10][i % 10] = Wc[i];
    if (t < 10) bcs[t] = bc[t];
    __syncthreads();
#pragma unroll
    for (int it = 0; it < 3; it++) {
        int idx = it * 256 + t;
        if (idx < 640) {
            int r = idx / 10, c = idx - r * 10;
            float acc = bcs[c];
#pragma unroll
            for (int j = 0; j < 64; j++) acc += Xs[r][j] * Wcs[j][c];
            out[(size_t)(r0 + r) * NC + c] = acc;
        }
    }
}

// ---------------------------------------------------------------------------
extern "C" void kernel_launch(void* const* d_in, const int* in_sizes, int n_in,
                              void* d_out, int out_size, void* d_ws, size_t ws_size,
                              hipStream_t stream) {
    const float* A   = (const float*)d_in[0];
    const float* emb = (const float*)d_in[1];
    const float* W1  = (const float*)d_in[2];
    const float* W2  = (const float*)d_in[3];
    const float* Wc  = (const float*)d_in[4];
    const float* bc  = (const float*)d_in[5];
    char* ws = (char*)d_ws;

    unsigned short* Abf  = (unsigned short*)(ws);                 // 134,217,728 B
    float* dvec          = (float*)(ws + 134217728);              //      32,768 B
    unsigned short* yT   = (unsigned short*)(ws + 134250496);     //   1,048,576 B
    float* partial       = (float*)(ws + 135299072);              //  16,777,216 B (SK=8)
    float* out           = (float*)d_out;

    rowsum_cast<<<N, 256, 0, stream>>>(A, Abf, dvec);

    // layer 1
    xw_from_global<<<N / 64, 256, 0, stream>>>(emb, W1, dvec, yT);
    spmm<<<dim3(N / BM, SK), 256, 0, stream>>>(Abf, yT, partial);

    // layer 2 (combine fused with xw)
    combine_xw<<<N / 64, 256, 0, stream>>>((const vf4*)partial, W2, dvec, yT);
    spmm<<<dim3(N / BM, SK), 256, 0, stream>>>(Abf, yT, partial);

    // epilogue (combine fused with classifier)
    combine_logits<<<N / 64, 256, 0, stream>>>((const vf4*)partial, dvec, Wc, bc, out);
}